// Round 1
// baseline (2760.240 us; speedup 1.0000x reference)
//
#include <hip/hip_runtime.h>

#define DIN 128

typedef __attribute__((ext_vector_type(8))) short bf16x8;
typedef __attribute__((ext_vector_type(4))) float f32x4;

// quantize one f32 to integer-valued bf16: q = clip(rint(x/s), -127, 127)
// rintf = round-half-even = jnp.round. q is an integer |q|<=127 -> exact in bf16
// (top 16 bits of the f32 pattern, no rounding needed).
__device__ inline unsigned short quant_bf16(float x, float s) {
  float q = rintf(x / s);
  q = fminf(fmaxf(q, -127.0f), 127.0f);
  return (unsigned short)(__float_as_uint(q) >> 16);
}

__device__ inline float wave_max(float m) {
#pragma unroll
  for (int off = 32; off > 0; off >>= 1)
    m = fmaxf(m, __shfl_down(m, off));
  return m;
}

// grid-stride absmax over n4 float4's -> atomicMax on float bits (exact for >=0)
__global__ void absmax_kernel(const float* __restrict__ X, int n4,
                              unsigned int* __restrict__ slot) {
  float m = 0.0f;
  int stride = gridDim.x * blockDim.x;
  for (int i = blockIdx.x * blockDim.x + threadIdx.x; i < n4; i += stride) {
    float4 v = ((const float4*)X)[i];
    m = fmaxf(m, fmaxf(fmaxf(fabsf(v.x), fabsf(v.y)),
                       fmaxf(fabsf(v.z), fabsf(v.w))));
  }
  m = wave_max(m);
  if ((threadIdx.x & 63) == 0) atomicMax(slot, __float_as_uint(m));
}

// one block (1024 thr) per 128x128 weight matrix: absmax -> slot, quantize -> bf16 ints
__global__ void prep_weights(const float* __restrict__ W0, const float* __restrict__ W1,
                             const float* __restrict__ W2, const float* __restrict__ W3,
                             unsigned short* __restrict__ Q0, unsigned short* __restrict__ Q1,
                             unsigned short* __restrict__ Q2, unsigned short* __restrict__ Q3,
                             unsigned int* __restrict__ slots) {
  const float* W = (blockIdx.x == 0) ? W0 : (blockIdx.x == 1) ? W1 : (blockIdx.x == 2) ? W2 : W3;
  unsigned short* Q = (blockIdx.x == 0) ? Q0 : (blockIdx.x == 1) ? Q1 : (blockIdx.x == 2) ? Q2 : Q3;
  __shared__ float red[16];
  __shared__ float s_sh;
  int t = threadIdx.x;  // 1024 threads, 16 waves
  float vals[16];
  float m = 0.0f;
#pragma unroll
  for (int i = 0; i < 16; ++i) {
    vals[i] = W[t + i * 1024];
    m = fmaxf(m, fabsf(vals[i]));
  }
  m = wave_max(m);
  if ((t & 63) == 0) red[t >> 6] = m;
  __syncthreads();
  if (t < 64) {
    float mm = (t < 16) ? red[t] : 0.0f;
    mm = wave_max(mm);
    if (t == 0) {
      slots[4 + blockIdx.x] = __float_as_uint(mm);
      s_sh = fmaxf(mm / 127.0f, 1e-12f);
    }
  }
  __syncthreads();
  float s = s_sh;
#pragma unroll
  for (int i = 0; i < 16; ++i) Q[t + i * 1024] = quant_bf16(vals[i], s);
}

// one 32-lane group per edge: SUM[dst] += X[src] (float4 per lane), CNT[dst] += 1
__global__ void scatter_add_kernel(const float* __restrict__ X, const int* __restrict__ src,
                                   const int* __restrict__ dst, float* __restrict__ SUM,
                                   float* __restrict__ CNT, int E) {
  long t = (long)blockIdx.x * blockDim.x + threadIdx.x;
  int lane = (int)(t & 31);
  long e = t >> 5;
  if (e >= E) return;
  int s = src[e];
  int d = dst[e];
  float4 v = ((const float4*)(X + (long)s * DIN))[lane];
  float* orow = SUM + (long)d * DIN + (long)lane * 4;
  atomicAdd(orow + 0, v.x);
  atomicAdd(orow + 1, v.y);
  atomicAdd(orow + 2, v.z);
  atomicAdd(orow + 3, v.w);
  if (lane == 0) atomicAdd(CNT + d, 1.0f);
}

// SUM /= max(cnt,1) in place (true division to match reference rounding), fused absmax
__global__ void finalize_kernel(float* __restrict__ SUM, const float* __restrict__ CNT,
                                int n4, unsigned int* __restrict__ slot) {
  float m = 0.0f;
  int stride = gridDim.x * blockDim.x;
  for (int i = blockIdx.x * blockDim.x + threadIdx.x; i < n4; i += stride) {
    int node = i >> 5;  // 32 float4 per 128-wide row
    float c = fmaxf(CNT[node], 1.0f);
    float4 v = ((const float4*)SUM)[i];
    v.x /= c; v.y /= c; v.z /= c; v.w /= c;
    ((float4*)SUM)[i] = v;
    m = fmaxf(m, fmaxf(fmaxf(fabsf(v.x), fabsf(v.y)),
                       fmaxf(fabsf(v.z), fabsf(v.w))));
  }
  m = wave_max(m);
  if ((threadIdx.x & 63) == 0) atomicMax(slot, __float_as_uint(m));
}

// Fused: OUT[m][:] = sx*swr * (qX @ qWroot^T) + sg*swl * (qAgg @ qWrel^T)
// qAgg is read from OUT itself (agg stored where output goes; block reads only its own rows).
// 256 thr = 4 waves; 64 rows/block; each wave: 16 rows x 128 cols via 8 16x16 frags.
// mfma_f32_16x16x32_bf16: A[m][k]: m=lane&15, k=(lane>>4)*8+e ; B[k][n]: n=lane&15, same k
// D[m][n]: n=lane&15, m=(lane>>4)*4+j  (verified layout)
__global__ __launch_bounds__(256) void gemm_fused(
    const float* __restrict__ X, float* __restrict__ OUT,
    const unsigned short* __restrict__ QWroot, const unsigned short* __restrict__ QWrel,
    const unsigned int* __restrict__ slots,
    int slot_x, int slot_g, int slot_wr, int slot_wl) {
  const int lane = threadIdx.x & 63;
  const int wv = threadIdx.x >> 6;
  const int r = lane & 15;
  const int g = lane >> 4;
  const long m0 = (long)blockIdx.x * 64;
  const long rowA = m0 + wv * 16 + r;

  const float s_x  = fmaxf(__uint_as_float(slots[slot_x]) / 127.0f, 1e-12f);
  const float s_g  = fmaxf(__uint_as_float(slots[slot_g]) / 127.0f, 1e-12f);
  const float s_wr = fmaxf(__uint_as_float(slots[slot_wr]) / 127.0f, 1e-12f);
  const float s_wl = fmaxf(__uint_as_float(slots[slot_wl]) / 127.0f, 1e-12f);

  const float* xrow = X + rowA * DIN;
  const float* grow = OUT + rowA * DIN;

  f32x4 acc_r[8], acc_l[8];
#pragma unroll
  for (int f = 0; f < 8; ++f) {
    acc_r[f] = {0.f, 0.f, 0.f, 0.f};
    acc_l[f] = {0.f, 0.f, 0.f, 0.f};
  }

#pragma unroll
  for (int kk = 0; kk < 4; ++kk) {
    const int k0 = kk * 32 + g * 8;
    float4 v0 = *(const float4*)(xrow + k0);
    float4 v1 = *(const float4*)(xrow + k0 + 4);
    float4 u0 = *(const float4*)(grow + k0);
    float4 u1 = *(const float4*)(grow + k0 + 4);
    float vx[8] = {v0.x, v0.y, v0.z, v0.w, v1.x, v1.y, v1.z, v1.w};
    float vg[8] = {u0.x, u0.y, u0.z, u0.w, u1.x, u1.y, u1.z, u1.w};
    bf16x8 ax, ag;
#pragma unroll
    for (int e = 0; e < 8; ++e) {
      ax[e] = (short)quant_bf16(vx[e], s_x);
      ag[e] = (short)quant_bf16(vg[e], s_g);
    }
#pragma unroll
    for (int f = 0; f < 8; ++f) {
      const int woff = (f * 16 + r) * DIN + k0;
      bf16x8 bR = *(const bf16x8*)(QWroot + woff);
      bf16x8 bL = *(const bf16x8*)(QWrel + woff);
      acc_r[f] = __builtin_amdgcn_mfma_f32_16x16x32_bf16(ax, bR, acc_r[f], 0, 0, 0);
      acc_l[f] = __builtin_amdgcn_mfma_f32_16x16x32_bf16(ag, bL, acc_l[f], 0, 0, 0);
    }
  }

  const float sc_r = s_x * s_wr;
  const float sc_l = s_g * s_wl;
  const long orow = m0 + wv * 16 + g * 4;
#pragma unroll
  for (int f = 0; f < 8; ++f) {
#pragma unroll
    for (int j = 0; j < 4; ++j) {
      OUT[(orow + j) * DIN + f * 16 + r] = acc_r[f][j] * sc_r + acc_l[f][j] * sc_l;
    }
  }
}

extern "C" void kernel_launch(void* const* d_in, const int* in_sizes, int n_in,
                              void* d_out, int out_size, void* d_ws, size_t ws_size,
                              hipStream_t stream) {
  const float* x_a      = (const float*)d_in[0];
  const float* x_b      = (const float*)d_in[1];
  const float* w_root_a = (const float*)d_in[2];
  const float* w_root_b = (const float*)d_in[3];
  const float* w_rel1   = (const float*)d_in[4];
  const float* w_rel2   = (const float*)d_in[5];
  const int* e1s = (const int*)d_in[6];
  const int* e1d = (const int*)d_in[7];
  const int* e2s = (const int*)d_in[8];
  const int* e2d = (const int*)d_in[9];

  const int NA = in_sizes[0] / DIN;
  const int NB = in_sizes[1] / DIN;
  const int E1 = in_sizes[6];
  const int E2 = in_sizes[8];

  float* out   = (float*)d_out;
  float* out_a = out;                       // [NA,128]; also agg2 accumulator
  float* out_b = out + (size_t)NA * DIN;    // [NB,128]; also agg1 accumulator

  // ws layout: slots[8] | cnt1[NB] | cnt2[NA] | 4x quantized weights (bf16)
  char* ws = (char*)d_ws;
  unsigned int* slots = (unsigned int*)ws;  // 0:xa 1:xb 2:agg1 3:agg2 4:wra 5:wrb 6:wr1 7:wr2
  size_t off = 1024;
  float* cnt1 = (float*)(ws + off); off += (size_t)NB * 4;
  float* cnt2 = (float*)(ws + off); off += (size_t)NA * 4;
  size_t zero_bytes = off;
  off = (off + 255) & ~(size_t)255;
  unsigned short* qw_ra = (unsigned short*)(ws + off); off += DIN * DIN * 2;
  unsigned short* qw_rb = (unsigned short*)(ws + off); off += DIN * DIN * 2;
  unsigned short* qw_r1 = (unsigned short*)(ws + off); off += DIN * DIN * 2;
  unsigned short* qw_r2 = (unsigned short*)(ws + off); off += DIN * DIN * 2;

  // zero accumulators (d_out doubles as agg sum buffer) and counts/slots
  hipMemsetAsync(d_out, 0, (size_t)out_size * 4, stream);
  hipMemsetAsync(d_ws, 0, zero_bytes, stream);

  // input absmax
  absmax_kernel<<<2048, 256, 0, stream>>>(x_a, in_sizes[0] / 4, slots + 0);
  absmax_kernel<<<2048, 256, 0, stream>>>(x_b, in_sizes[1] / 4, slots + 1);

  // weight absmax + quantize (one block per matrix)
  prep_weights<<<4, 1024, 0, stream>>>(w_root_a, w_root_b, w_rel1, w_rel2,
                                       qw_ra, qw_rb, qw_r1, qw_r2, slots);

  // segment sums: agg1 (x_a over edge1 -> b nodes) into out_b region; agg2 into out_a region
  {
    int blocks1 = (int)(((long)E1 * 32 + 255) / 256);
    int blocks2 = (int)(((long)E2 * 32 + 255) / 256);
    scatter_add_kernel<<<blocks1, 256, 0, stream>>>(x_a, e1s, e1d, out_b, cnt1, E1);
    scatter_add_kernel<<<blocks2, 256, 0, stream>>>(x_b, e2s, e2d, out_a, cnt2, E2);
  }

  // mean + absmax of aggregates
  finalize_kernel<<<2048, 256, 0, stream>>>(out_b, cnt1, NB * 32, slots + 2);
  finalize_kernel<<<2048, 256, 0, stream>>>(out_a, cnt2, NA * 32, slots + 3);

  // fused quant-GEMMs: out_a = fq(x_a)@fq(w_root_a)^T + fq(agg2)@fq(w_rel2)^T ; similarly out_b
  gemm_fused<<<NA / 64, 256, 0, stream>>>(x_a, out_a, qw_ra, qw_r2, slots, 0, 3, 4, 7);
  gemm_fused<<<NB / 64, 256, 0, stream>>>(x_b, out_b, qw_rb, qw_r1, slots, 1, 2, 5, 6);
}